// Round 1
// baseline (168.583 us; speedup 1.0000x reference)
//
#include <hip/hip_runtime.h>
#include <stdint.h>

#define B_DIM 8
#define S_LEN 2048
#define DMODEL 2048
#define HDIM 128

typedef __attribute__((ext_vector_type(4))) float f32x4;
typedef __attribute__((ext_vector_type(8))) short bf16x8;
typedef __attribute__((ext_vector_type(4))) short bf16x4;
typedef unsigned short u16;
typedef unsigned int u32;

__device__ __forceinline__ u16 f2bf(float f) {
    union { float f; u32 u; } v; v.f = f;
    u32 u = v.u;
    u32 r = (u + 0x7fffu + ((u >> 16) & 1u)) >> 16;
    return (u16)r;
}

__device__ __forceinline__ void async_copy16(u16* lds, const u16* g) {
    __builtin_amdgcn_global_load_lds((const __attribute__((address_space(1))) u32*)g,
                                     (__attribute__((address_space(3))) u32*)lds,
                                     16, 0, 0);
}

// ---------------- pack weights: [2048][128] fp32 x3 -> bf16 Wt[384 n][2048 k]
__global__ void pack_weights(const float* __restrict__ Wq, const float* __restrict__ Wk,
                             const float* __restrict__ Wv, u16* __restrict__ Wp) {
    int idx = blockIdx.x * 256 + threadIdx.x;       // 3*128*2048 = 786432
    int w = idx >> 18;                              // which weight
    int rem = idx & 262143;
    int h = rem >> 11;                              // head-dim col
    int k = rem & 2047;                             // d_model row
    const float* W = (w == 0) ? Wq : ((w == 1) ? Wk : Wv);
    Wp[idx] = f2bf(W[k * HDIM + h]);
}

// ---------------- fused QKV projection GEMM: [16384,2048] @ [2048,384] (bf16 MFMA)
__launch_bounds__(256)
__global__ void qkv_gemm(const float* __restrict__ hs, const u16* __restrict__ Wp,
                         const float* __restrict__ bq, const float* __restrict__ bk,
                         const float* __restrict__ bv,
                         u16* __restrict__ Qb, u16* __restrict__ Kb, u16* __restrict__ Vb) {
    __shared__ u16 As[64 * 64];     // [64 m][64 k] bf16, 16B-slot XOR swizzled
    __shared__ u16 Bs[384 * 64];    // [384 n][64 k] bf16, swizzled

    int t = threadIdx.x;
    int wv = t >> 6, l = t & 63, lr = l & 15, lq = l >> 4;
    int m0 = blockIdx.x * 64;

    f32x4 acc[4][6];
#pragma unroll
    for (int m = 0; m < 4; m++)
#pragma unroll
        for (int n = 0; n < 6; n++) acc[m][n] = (f32x4)0.f;

    int ar = t >> 2;        // A staging: row per 4 threads
    int aq4 = t & 3;        // 16-float column chunk

    for (int k0 = 0; k0 < DMODEL; k0 += 64) {
        // stage A: fp32 -> bf16, swizzled ds_write_b64
        const float* ga = hs + (size_t)(m0 + ar) * DMODEL + k0 + aq4 * 16;
#pragma unroll
        for (int j = 0; j < 4; j++) {
            f32x4 v = *(const f32x4*)(ga + j * 4);
            bf16x4 p;
            p.x = (short)f2bf(v.x); p.y = (short)f2bf(v.y);
            p.z = (short)f2bf(v.z); p.w = (short)f2bf(v.w);
            int colb = (aq4 * 16 + j * 4) * 2;          // byte col in row (0..127)
            int slot = colb >> 4;
            int within = colb & 15;
            int phys = ar * 128 + ((slot ^ (ar & 7)) << 4) + within;
            *(bf16x4*)((char*)As + phys) = p;
        }
        // stage B: global_load_lds with inverse-swizzled per-lane source
#pragma unroll
        for (int i = 0; i < 12; i++) {
            int c = i * 256 + t;                        // 16B chunk id, 3072 total
            int n = c >> 3, s = c & 7;
            int j = s ^ (n & 7);
            async_copy16(Bs + c * 8, Wp + n * 2048 + k0 + j * 8);
        }
        __syncthreads();

#pragma unroll
        for (int kk2 = 0; kk2 < 2; kk2++) {
            bf16x8 a[4], b[6];
#pragma unroll
            for (int m = 0; m < 4; m++) {
                int row = m * 16 + lr;
                int slot = kk2 * 4 + lq;
                a[m] = *(bf16x8*)((char*)As + row * 128 + ((slot ^ (row & 7)) << 4));
            }
#pragma unroll
            for (int n = 0; n < 6; n++) {
                int row = wv * 96 + n * 16 + lr;
                int slot = kk2 * 4 + lq;
                b[n] = *(bf16x8*)((char*)Bs + row * 128 + ((slot ^ (row & 7)) << 4));
            }
#pragma unroll
            for (int m = 0; m < 4; m++)
#pragma unroll
                for (int n = 0; n < 6; n++)
                    acc[m][n] = __builtin_amdgcn_mfma_f32_16x16x32_bf16(a[m], b[n], acc[m][n], 0, 0, 0);
        }
        __syncthreads();
    }

    // epilogue: bias, Q pre-scale by 1/sqrt(128), store bf16
#pragma unroll
    for (int n = 0; n < 6; n++) {
        int col = wv * 96 + n * 16 + lr;
        int w = col >> 7, h = col & 127;
        const float* bp = (w == 0) ? bq : ((w == 1) ? bk : bv);
        float bias = bp[h];
        float scale = (w == 0) ? 0.08838834764831845f : 1.0f;
        u16* dst = (w == 0) ? Qb : ((w == 1) ? Kb : Vb);
#pragma unroll
        for (int m = 0; m < 4; m++) {
#pragma unroll
            for (int r = 0; r < 4; r++) {
                int row = m0 + m * 16 + lq * 4 + r;
                dst[(size_t)row * HDIM + h] = f2bf((acc[m][n][r] + bias) * scale);
            }
        }
    }
}

// ---------------- V transpose: [b][s][d] -> [b][d][s] (bf16)
__global__ void transpose_v(const u16* __restrict__ Vb, u16* __restrict__ Vt) {
    int o = blockIdx.x * 256 + threadIdx.x;         // 2,097,152 total
    int b = o >> 18;
    int rem = o & 262143;
    int d = rem >> 11;
    int s = rem & 2047;
    Vt[o] = Vb[(size_t)(b * S_LEN + s) * HDIM + d];
}

// ---------------- causal flash attention
__launch_bounds__(128)
__global__ void attn(const u16* __restrict__ Qb, const u16* __restrict__ Kb,
                     const u16* __restrict__ Vt, float* __restrict__ out) {
    __shared__ u16 Ks[64 * 128];    // [kv][d], 256B rows, 16-slot swizzle
    __shared__ u16 Vs[128 * 64];    // [d][kv], 128B rows, 8-slot swizzle
    __shared__ u16 Ps[2 * 16 * 64]; // per-wave P tile [16 q][64 kv], swizzled

    int t = threadIdx.x;
    int wv = t >> 6, l = t & 63, lr = l & 15, lq = l >> 4;
    int bx = blockIdx.x;
    int b = bx >> 6;
    int qt = 63 - (bx & 63);        // descending work order: heavy tiles first
    int qr0 = qt * 32 + wv * 16;
    size_t qbase = (size_t)b * S_LEN;

    // Q fragments straight from global (once)
    bf16x8 aq[4];
#pragma unroll
    for (int kk = 0; kk < 4; kk++)
        aq[kk] = *(const bf16x8*)(Qb + (qbase + qr0 + lr) * HDIM + kk * 32 + lq * 8);

    f32x4 o_acc[8];
#pragma unroll
    for (int n = 0; n < 8; n++) o_acc[n] = (f32x4)0.f;
    float m_run[4], l_run[4];
#pragma unroll
    for (int r = 0; r < 4; r++) { m_run[r] = -1e38f; l_run[r] = 0.f; }

    int nkt = (qt >> 1) + 1;
    int ktd = qt >> 1;
    u16* Pw = Ps + wv * 16 * 64;

    for (int kt = 0; kt < nkt; ++kt) {
        int kv0 = kt * 64;
        // stage K tile (64x128 bf16 = 16KB): 8 issues of global_load_lds x16B
#pragma unroll
        for (int i = 0; i < 8; i++) {
            int c = i * 128 + t;
            int n = c >> 4, s = c & 15;
            int j = s ^ (n & 15);
            async_copy16(Ks + c * 8, Kb + (qbase + kv0 + n) * HDIM + j * 8);
        }
        // stage Vt tile (128x64 bf16 = 16KB)
#pragma unroll
        for (int i = 0; i < 8; i++) {
            int c = i * 128 + t;
            int dd = c >> 3, s = c & 7;
            int j = s ^ (dd & 7);
            async_copy16(Vs + c * 8, Vt + (size_t)(b * HDIM + dd) * S_LEN + kv0 + j * 8);
        }
        __syncthreads();

        // S = Q K^T (pre-scaled Q)
        f32x4 sa[4];
#pragma unroll
        for (int n = 0; n < 4; n++) sa[n] = (f32x4)0.f;
#pragma unroll
        for (int kk = 0; kk < 4; kk++) {
            int slot = kk * 4 + lq;
#pragma unroll
            for (int n = 0; n < 4; n++) {
                int row = n * 16 + lr;
                bf16x8 bk8 = *(bf16x8*)((char*)Ks + row * 256 + ((slot ^ (row & 15)) << 4));
                sa[n] = __builtin_amdgcn_mfma_f32_16x16x32_bf16(aq[kk], bk8, sa[n], 0, 0, 0);
            }
        }
        // causal mask on the diagonal tile
        if (kt == ktd) {
#pragma unroll
            for (int n = 0; n < 4; n++) {
                int col = kv0 + n * 16 + lr;
#pragma unroll
                for (int r = 0; r < 4; r++) {
                    int row = qr0 + lq * 4 + r;
                    if (col > row) sa[n][r] = -1e30f;
                }
            }
        }
        // online softmax (16-lane groups own 4 q-rows each, one per reg)
        float pexp[4][4];
#pragma unroll
        for (int r = 0; r < 4; r++) {
            float mx = fmaxf(fmaxf(sa[0][r], sa[1][r]), fmaxf(sa[2][r], sa[3][r]));
#pragma unroll
            for (int off = 8; off >= 1; off >>= 1) mx = fmaxf(mx, __shfl_xor(mx, off, 64));
            float mnew = fmaxf(m_run[r], mx);
            float f = __expf(m_run[r] - mnew);
            float rs = 0.f;
#pragma unroll
            for (int n = 0; n < 4; n++) { float e = __expf(sa[n][r] - mnew); pexp[n][r] = e; rs += e; }
#pragma unroll
            for (int off = 8; off >= 1; off >>= 1) rs += __shfl_xor(rs, off, 64);
            l_run[r] = l_run[r] * f + rs;
            m_run[r] = mnew;
#pragma unroll
            for (int n = 0; n < 8; n++) o_acc[n][r] *= f;
        }
        // P -> LDS (bf16, swizzled) to re-layout into A-fragments
#pragma unroll
        for (int n = 0; n < 4; n++) {
            int col = n * 16 + lr;
            int slot = col >> 3;
            int within = (col & 7) * 2;
#pragma unroll
            for (int r = 0; r < 4; r++) {
                int row = lq * 4 + r;
                *(u16*)((char*)Pw + row * 128 + ((slot ^ (row & 7)) << 4) + within) = f2bf(pexp[n][r]);
            }
        }
        __syncthreads();
        // O += P V
#pragma unroll
        for (int kk = 0; kk < 2; kk++) {
            int slot = kk * 4 + lq;
            bf16x8 pa = *(bf16x8*)((char*)Pw + lr * 128 + ((slot ^ (lr & 7)) << 4));
#pragma unroll
            for (int n = 0; n < 8; n++) {
                int row = n * 16 + lr;
                bf16x8 vb8 = *(bf16x8*)((char*)Vs + row * 128 + ((slot ^ (row & 7)) << 4));
                o_acc[n] = __builtin_amdgcn_mfma_f32_16x16x32_bf16(pa, vb8, o_acc[n], 0, 0, 0);
            }
        }
        __syncthreads();
    }

    // epilogue: normalize and store fp32
#pragma unroll
    for (int r = 0; r < 4; r++) {
        float inv = 1.0f / l_run[r];
        int row = qr0 + lq * 4 + r;
#pragma unroll
        for (int n = 0; n < 8; n++) {
            int col = n * 16 + lr;
            out[(qbase + row) * HDIM + col] = o_acc[n][r] * inv;
        }
    }
}

extern "C" void kernel_launch(void* const* d_in, const int* in_sizes, int n_in,
                              void* d_out, int out_size, void* d_ws, size_t ws_size,
                              hipStream_t stream) {
    const float* hs = (const float*)d_in[0];
    const float* Wq = (const float*)d_in[1];
    const float* bq = (const float*)d_in[2];
    const float* Wk = (const float*)d_in[3];
    const float* bk = (const float*)d_in[4];
    const float* Wv = (const float*)d_in[5];
    const float* bv = (const float*)d_in[6];
    float* out = (float*)d_out;

    char* ws = (char*)d_ws;
    u16* Qb = (u16*)(ws);                       // 4 MB  [16384][128] bf16 (pre-scaled)
    u16* Kb = (u16*)(ws + (size_t)(4  << 20));  // 4 MB
    u16* Vb = (u16*)(ws + (size_t)(8  << 20));  // 4 MB
    u16* Vt = (u16*)(ws + (size_t)(12 << 20));  // 4 MB  [8][128][2048]
    u16* Wp = (u16*)(ws + (size_t)(16 << 20));  // 1.5 MB [384][2048]

    hipLaunchKernelGGL(pack_weights, dim3(3072), dim3(256), 0, stream, Wq, Wk, Wv, Wp);
    hipLaunchKernelGGL(qkv_gemm, dim3(256), dim3(256), 0, stream, hs, Wp, bq, bk, bv, Qb, Kb, Vb);
    hipLaunchKernelGGL(transpose_v, dim3(8192), dim3(256), 0, stream, Vb, Vt);
    hipLaunchKernelGGL(attn, dim3(512), dim3(128), 0, stream, Qb, Kb, Vt, out);
}

// Round 2
// 156.509 us; speedup vs baseline: 1.0771x; 1.0771x over previous
//
#include <hip/hip_runtime.h>
#include <stdint.h>

#define B_DIM 8
#define S_LEN 2048
#define DMODEL 2048
#define HDIM 128

typedef __attribute__((ext_vector_type(4))) float f32x4;
typedef __attribute__((ext_vector_type(8))) short bf16x8;
typedef unsigned short u16;
typedef unsigned int u32;

__device__ __forceinline__ u16 f2bf(float f) {
    union { float f; u32 u; } v; v.f = f;
    u32 u = v.u;
    u32 r = (u + 0x7fffu + ((u >> 16) & 1u)) >> 16;
    return (u16)r;
}

__device__ __forceinline__ void async_copy16(u16* lds, const u16* g) {
    __builtin_amdgcn_global_load_lds((const __attribute__((address_space(1))) u32*)g,
                                     (__attribute__((address_space(3))) u32*)lds,
                                     16, 0, 0);
}

// ---------------- pack weights: transpose [2048 k][128 h] fp32 x3 -> bf16 Wp[384 h][2048 k]
// LDS-tiled 64x64 for coalesced read AND write.
__global__ void pack_weights(const float* __restrict__ Wq, const float* __restrict__ Wk,
                             const float* __restrict__ Wv, u16* __restrict__ Wp) {
    __shared__ u16 tl[64 * 64];          // rows of 128B, 16B-slot XOR swizzle
    int t = threadIdx.x;
    int bx = blockIdx.x;                 // 3 w * 32 kt * 2 ht = 192
    int w = bx >> 6;
    int kt = (bx >> 1) & 31;
    int ht = bx & 1;
    int k0 = kt * 64, h0 = ht * 64;
    const float* W = (w == 0) ? Wq : ((w == 1) ? Wk : Wv);

    int kl = t >> 2, hc = t & 3;
    const float* src = W + (size_t)(k0 + kl) * HDIM + h0 + hc * 16;
#pragma unroll
    for (int half = 0; half < 2; half++) {
        bf16x8 p;
#pragma unroll
        for (int j = 0; j < 8; j++) p[j] = (short)f2bf(src[half * 8 + j]);
        int slot = hc * 2 + half;
        *(bf16x8*)((char*)tl + kl * 128 + ((slot ^ (kl & 7)) << 4)) = p;
    }
    __syncthreads();
    int hl = t >> 2, kc = t & 3;
    u16* dst = Wp + (size_t)(w * HDIM + h0 + hl) * DMODEL + k0 + kc * 16;
#pragma unroll
    for (int half = 0; half < 2; half++) {
        bf16x8 p;
#pragma unroll
        for (int j = 0; j < 8; j++) {
            int k = kc * 16 + half * 8 + j;
            p[j] = *(u16*)((char*)tl + k * 128 + (((hl >> 3) ^ (k & 7)) << 4) + (hl & 7) * 2);
        }
        *(bf16x8*)(dst + half * 8) = p;
    }
}

// ---------------- fused QKV projection GEMM: [16384,2048] @ [2048,384] (bf16 MFMA)
// BM=128, BN=192, BK=64, 8 waves (2m x 4n, wave tile 64x48), double-buffered 2-phase pipeline.
__launch_bounds__(512, 2)
__global__ void qkv_gemm(const float* __restrict__ hs, const u16* __restrict__ Wp,
                         const float* __restrict__ bq, const float* __restrict__ bk,
                         const float* __restrict__ bv,
                         u16* __restrict__ Qb, u16* __restrict__ Kb, u16* __restrict__ Vb) {
    __shared__ u16 As[2][128 * 64];      // 2 x 16 KB
    __shared__ u16 Bs[2][192 * 64];      // 2 x 24 KB

    int t = threadIdx.x;
    int wv = t >> 6, l = t & 63, lr = l & 15, lq = l >> 4;
    int wm = wv >> 2, wn = wv & 3;
    int mt = blockIdx.x >> 1, nb = blockIdx.x & 1;
    int m0 = mt * 128, col0 = nb * 192;

    f32x4 acc[4][3] = {};

    int ar = t >> 2, aq = t & 3;         // A staging: row, 16-float chunk
    const float* gA = hs + (size_t)(m0 + ar) * DMODEL + aq * 16;

    f32x4 av[4];

#define LOAD_A(K0)                                                     \
    {                                                                  \
        _Pragma("unroll")                                              \
        for (int j = 0; j < 4; j++) av[j] = *(const f32x4*)(gA + (K0) + j * 4); \
    }
#define STAGE_B(K0, BUF)                                               \
    {                                                                  \
        _Pragma("unroll")                                              \
        for (int i = 0; i < 3; i++) {                                  \
            int c = i * 512 + t;                                       \
            int n = c >> 3, s = c & 7;                                 \
            async_copy16(&Bs[BUF][c * 8],                              \
                         Wp + (size_t)(col0 + n) * DMODEL + (K0) + ((s ^ (n & 7)) * 8)); \
        }                                                              \
    }
#define WRITE_A(BUF)                                                   \
    {                                                                  \
        bf16x8 p0, p1;                                                 \
        _Pragma("unroll")                                              \
        for (int j = 0; j < 4; j++) { p0[j] = (short)f2bf(av[0][j]); p0[4 + j] = (short)f2bf(av[1][j]); \
                                      p1[j] = (short)f2bf(av[2][j]); p1[4 + j] = (short)f2bf(av[3][j]); } \
        int slot0 = aq * 2;                                            \
        *(bf16x8*)((char*)&As[BUF][0] + ar * 128 + ((slot0 ^ (ar & 7)) << 4)) = p0; \
        *(bf16x8*)((char*)&As[BUF][0] + ar * 128 + (((slot0 + 1) ^ (ar & 7)) << 4)) = p1; \
    }

    // prologue: stage tile 0 into buffer 0
    LOAD_A(0);
    STAGE_B(0, 0);
    WRITE_A(0);
    __syncthreads();

    int cur = 0;
    for (int k0 = 0; k0 < DMODEL; k0 += 64) {
        int kn = (k0 + 64) & (DMODEL - 1);   // wraps to 0 on last step (junk, unused)
        LOAD_A(kn);
        STAGE_B(kn, cur ^ 1);
        // compute current buffer
#pragma unroll
        for (int kk = 0; kk < 2; kk++) {
            bf16x8 a[4], b[3];
            int slot = kk * 4 + lq;
#pragma unroll
            for (int mi = 0; mi < 4; mi++) {
                int row = wm * 64 + mi * 16 + lr;
                a[mi] = *(bf16x8*)((char*)&As[cur][0] + row * 128 + ((slot ^ (row & 7)) << 4));
            }
#pragma unroll
            for (int ni = 0; ni < 3; ni++) {
                int row = wn * 48 + ni * 16 + lr;
                b[ni] = *(bf16x8*)((char*)&Bs[cur][0] + row * 128 + ((slot ^ (row & 7)) << 4));
            }
#pragma unroll
            for (int mi = 0; mi < 4; mi++)
#pragma unroll
                for (int ni = 0; ni < 3; ni++)
                    acc[mi][ni] = __builtin_amdgcn_mfma_f32_16x16x32_bf16(a[mi], b[ni], acc[mi][ni], 0, 0, 0);
        }
        WRITE_A(cur ^ 1);
        __syncthreads();
        cur ^= 1;
    }

    // epilogue: bias, Q pre-scale by 1/sqrt(128), store bf16
#pragma unroll
    for (int ni = 0; ni < 3; ni++) {
        int col = col0 + wn * 48 + ni * 16 + lr;
        int w = col >> 7, h = col & 127;
        const float* bp = (w == 0) ? bq : ((w == 1) ? bk : bv);
        float bias = bp[h];
        float scale = (w == 0) ? 0.08838834764831845f : 1.0f;
        u16* dst = (w == 0) ? Qb : ((w == 1) ? Kb : Vb);
#pragma unroll
        for (int mi = 0; mi < 4; mi++) {
#pragma unroll
            for (int r = 0; r < 4; r++) {
                int row = m0 + wm * 64 + mi * 16 + lq * 4 + r;
                dst[(size_t)row * HDIM + h] = f2bf((acc[mi][ni][r] + bias) * scale);
            }
        }
    }
#undef LOAD_A
#undef STAGE_B
#undef WRITE_A
}

// ---------------- V transpose: [b][s][d] -> [b][d][s] (bf16), LDS-tiled 64x64
__global__ void transpose_v(const u16* __restrict__ Vb, u16* __restrict__ Vt) {
    __shared__ u16 tl[64 * 64];
    int t = threadIdx.x;
    int bx = blockIdx.x;                 // 8 b * 32 st * 2 dt = 512
    int b = bx >> 6;
    int st = (bx >> 1) & 31;
    int dt = bx & 1;
    int s0 = st * 64, d0 = dt * 64;

    int sl = t >> 2, dc = t & 3;
    const u16* src = Vb + (size_t)(b * S_LEN + s0 + sl) * HDIM + d0 + dc * 16;
#pragma unroll
    for (int half = 0; half < 2; half++) {
        bf16x8 p = *(const bf16x8*)(src + half * 8);
        int slot = dc * 2 + half;
        *(bf16x8*)((char*)tl + sl * 128 + ((slot ^ (sl & 7)) << 4)) = p;
    }
    __syncthreads();
    int dl = t >> 2, sc = t & 3;
    u16* dst = Vt + (size_t)(b * HDIM + d0 + dl) * S_LEN + s0 + sc * 16;
#pragma unroll
    for (int half = 0; half < 2; half++) {
        bf16x8 p;
#pragma unroll
        for (int j = 0; j < 8; j++) {
            int s = sc * 16 + half * 8 + j;
            p[j] = *(u16*)((char*)tl + s * 128 + (((dl >> 3) ^ (s & 7)) << 4) + (dl & 7) * 2);
        }
        *(bf16x8*)(dst + half * 8) = p;
    }
}

// ---------------- causal flash attention (double-buffered, 1 barrier/phase)
__launch_bounds__(128)
__global__ void attn(const u16* __restrict__ Qb, const u16* __restrict__ Kb,
                     const u16* __restrict__ Vt, float* __restrict__ out) {
    __shared__ u16 Ks[2][64 * 128];      // [kv][d], 256B rows, 16-slot swizzle
    __shared__ u16 Vs[2][128 * 64];      // [d][kv], 128B rows, 8-slot swizzle
    __shared__ u16 Ps[2][16 * 64];       // per-wave P tile (not double-buffered: wave-private)

    int t = threadIdx.x;
    int wv = t >> 6, l = t & 63, lr = l & 15, lq = l >> 4;
    int bx = blockIdx.x;
    int b = bx & 7;                      // batch == XCD (bx%8) for L2 KV locality
    int qt = 63 - (bx >> 3);             // descending work order
    int qr0 = qt * 32 + wv * 16;
    size_t qbase = (size_t)b * S_LEN;

    // Q fragments straight from global (once)
    bf16x8 aqf[4];
#pragma unroll
    for (int kk = 0; kk < 4; kk++)
        aqf[kk] = *(const bf16x8*)(Qb + (qbase + qr0 + lr) * HDIM + kk * 32 + lq * 8);

    f32x4 o_acc[8] = {};
    float m_run[4], l_run[4];
#pragma unroll
    for (int r = 0; r < 4; r++) { m_run[r] = -1e38f; l_run[r] = 0.f; }

    int nkt = (qt >> 1) + 1;
    int ktd = qt >> 1;
    u16* Pw = &Ps[wv][0];

#define STAGE_KV(KV0, BUF)                                             \
    {                                                                  \
        _Pragma("unroll")                                              \
        for (int i = 0; i < 8; i++) {                                  \
            int c = i * 128 + t;                                       \
            int n = c >> 4, s = c & 15;                                \
            async_copy16(&Ks[BUF][c * 8], Kb + (qbase + (KV0) + n) * HDIM + (s ^ (n & 15)) * 8); \
        }                                                              \
        _Pragma("unroll")                                              \
        for (int i = 0; i < 8; i++) {                                  \
            int c = i * 128 + t;                                       \
            int dd = c >> 3, s = c & 7;                                \
            async_copy16(&Vs[BUF][c * 8], Vt + (size_t)(b * HDIM + dd) * S_LEN + (KV0) + (s ^ (dd & 7)) * 8); \
        }                                                              \
    }

    STAGE_KV(0, 0);
    __syncthreads();

    for (int kt = 0; kt < nkt; ++kt) {
        int cur = kt & 1;
        int kv0 = kt * 64;
        int kvn = (kt + 1 < nkt) ? (kt + 1) * 64 : 0;   // junk prefetch on last phase (unused)
        STAGE_KV(kvn, cur ^ 1);

        // S = Q K^T (pre-scaled Q)
        f32x4 sa[4] = {};
#pragma unroll
        for (int kk = 0; kk < 4; kk++) {
            int slot = kk * 4 + lq;
#pragma unroll
            for (int n = 0; n < 4; n++) {
                int row = n * 16 + lr;
                bf16x8 bk8 = *(bf16x8*)((char*)&Ks[cur][0] + row * 256 + ((slot ^ (row & 15)) << 4));
                sa[n] = __builtin_amdgcn_mfma_f32_16x16x32_bf16(aqf[kk], bk8, sa[n], 0, 0, 0);
            }
        }
        // causal mask on the diagonal tile
        if (kt == ktd) {
#pragma unroll
            for (int n = 0; n < 4; n++) {
                int col = kv0 + n * 16 + lr;
#pragma unroll
                for (int r = 0; r < 4; r++) {
                    int row = qr0 + lq * 4 + r;
                    if (col > row) sa[n][r] = -1e30f;
                }
            }
        }
        // online softmax (16-lane groups own 4 q-rows each)
        float pexp[4][4];
#pragma unroll
        for (int r = 0; r < 4; r++) {
            float mx = fmaxf(fmaxf(sa[0][r], sa[1][r]), fmaxf(sa[2][r], sa[3][r]));
#pragma unroll
            for (int off = 8; off >= 1; off >>= 1) mx = fmaxf(mx, __shfl_xor(mx, off, 64));
            float mnew = fmaxf(m_run[r], mx);
            float f = __expf(m_run[r] - mnew);
            float rs = 0.f;
#pragma unroll
            for (int n = 0; n < 4; n++) { float e = __expf(sa[n][r] - mnew); pexp[n][r] = e; rs += e; }
#pragma unroll
            for (int off = 8; off >= 1; off >>= 1) rs += __shfl_xor(rs, off, 64);
            l_run[r] = l_run[r] * f + rs;
            m_run[r] = mnew;
#pragma unroll
            for (int n = 0; n < 8; n++) o_acc[n][r] *= f;
        }
        // P -> wave-private LDS (no barrier needed; in-wave lgkm ordering suffices)
#pragma unroll
        for (int n = 0; n < 4; n++) {
            int col = n * 16 + lr;
            int slot = col >> 3;
            int within = (col & 7) * 2;
#pragma unroll
            for (int r = 0; r < 4; r++) {
                int row = lq * 4 + r;
                *(u16*)((char*)Pw + row * 128 + ((slot ^ (row & 7)) << 4) + within) = f2bf(pexp[n][r]);
            }
        }
        // O += P V
#pragma unroll
        for (int kk = 0; kk < 2; kk++) {
            int slot = kk * 4 + lq;
            bf16x8 pa = *(bf16x8*)((char*)Pw + lr * 128 + ((slot ^ (lr & 7)) << 4));
#pragma unroll
            for (int n = 0; n < 8; n++) {
                int row = n * 16 + lr;
                bf16x8 vb8 = *(bf16x8*)((char*)&Vs[cur][0] + row * 128 + ((slot ^ (row & 7)) << 4));
                o_acc[n] = __builtin_amdgcn_mfma_f32_16x16x32_bf16(pa, vb8, o_acc[n], 0, 0, 0);
            }
        }
        __syncthreads();   // drains prefetch vmcnt + all lgkm; one barrier per phase
    }
#undef STAGE_KV

    // epilogue: normalize and store fp32
#pragma unroll
    for (int r = 0; r < 4; r++) {
        float inv = 1.0f / l_run[r];
        int row = qr0 + lq * 4 + r;
#pragma unroll
        for (int n = 0; n < 8; n++) {
            int col = n * 16 + lr;
            out[(qbase + row) * HDIM + col] = o_acc[n][r] * inv;
        }
    }
}

extern "C" void kernel_launch(void* const* d_in, const int* in_sizes, int n_in,
                              void* d_out, int out_size, void* d_ws, size_t ws_size,
                              hipStream_t stream) {
    const float* hs = (const float*)d_in[0];
    const float* Wq = (const float*)d_in[1];
    const float* bq = (const float*)d_in[2];
    const float* Wk = (const float*)d_in[3];
    const float* bk = (const float*)d_in[4];
    const float* Wv = (const float*)d_in[5];
    const float* bv = (const float*)d_in[6];
    float* out = (float*)d_out;

    char* ws = (char*)d_ws;
    u16* Qb = (u16*)(ws);                       // 4 MB  [16384][128] bf16 (pre-scaled)
    u16* Kb = (u16*)(ws + (size_t)(4  << 20));  // 4 MB
    u16* Vb = (u16*)(ws + (size_t)(8  << 20));  // 4 MB
    u16* Vt = (u16*)(ws + (size_t)(12 << 20));  // 4 MB  [8][128][2048]
    u16* Wp = (u16*)(ws + (size_t)(16 << 20));  // 1.5 MB [384][2048]

    hipLaunchKernelGGL(pack_weights, dim3(192), dim3(256), 0, stream, Wq, Wk, Wv, Wp);
    hipLaunchKernelGGL(qkv_gemm, dim3(256), dim3(512), 0, stream, hs, Wp, bq, bk, bv, Qb, Kb, Vb);
    hipLaunchKernelGGL(transpose_v, dim3(512), dim3(256), 0, stream, Vb, Vt);
    hipLaunchKernelGGL(attn, dim3(512), dim3(128), 0, stream, Qb, Kb, Vt, out);
}